// Round 1
// baseline (2486.384 us; speedup 1.0000x reference)
//
#include <hip/hip_runtime.h>

#define H 2048
#define E 16
#define F 1408
#define FS 4096
#define T 2048
#define TOPK 4
#define CAP 2048
#define LDA 40  // padded LDS row stride in bf16 elements (80 B, 16B-aligned, 2-way-bank-free)

typedef __bf16 bf16;
typedef bf16 bf16x4 __attribute__((ext_vector_type(4)));
typedef bf16 bf16x8 __attribute__((ext_vector_type(8)));
typedef float floatx4 __attribute__((ext_vector_type(4)));

static __device__ __forceinline__ floatx4 mfma16(bf16x8 a, bf16x8 b, floatx4 c) {
    return __builtin_amdgcn_mfma_f32_16x16x32_bf16(a, b, c, 0, 0, 0);
}

// ---------------- router: fp32 logits, softmax, top-4, scatter ----------------
__global__ __launch_bounds__(256) void router_kernel(
    const float* __restrict__ x, const float* __restrict__ wr,
    int* __restrict__ cnt, int* __restrict__ tokid, float* __restrict__ tokw) {
    const int wave = threadIdx.x >> 6;
    const int lane = threadIdx.x & 63;
    const int t = blockIdx.x * 4 + wave;
    if (t >= T) return;
    const float* xrow = x + (size_t)t * H;
    float xr[H / 64];
#pragma unroll
    for (int i = 0; i < H / 64; i++) xr[i] = xrow[lane + i * 64];
    float logits[E];
    for (int e = 0; e < E; e++) {
        const float* wrow = wr + (size_t)e * H;
        float p = 0.f;
#pragma unroll
        for (int i = 0; i < H / 64; i++) p += xr[i] * wrow[lane + i * 64];
        for (int off = 32; off; off >>= 1) p += __shfl_xor(p, off, 64);
        logits[e] = p;
    }
    float mx = logits[0];
    for (int e = 1; e < E; e++) mx = fmaxf(mx, logits[e]);
    float pr[E];
    float sum = 0.f;
    for (int e = 0; e < E; e++) { pr[e] = __expf(logits[e] - mx); sum += pr[e]; }
    float inv = 1.f / sum;
    for (int e = 0; e < E; e++) pr[e] *= inv;
    int sel[TOPK]; float sw[TOPK]; float wsum = 0.f;
    for (int k = 0; k < TOPK; k++) {
        float best = -1.f; int bi = 0;
        for (int e = 0; e < E; e++) if (pr[e] > best) { best = pr[e]; bi = e; }
        sel[k] = bi; sw[k] = best; wsum += best; pr[bi] = -2.f;
    }
    if (lane == 0) {
        float invw = 1.f / wsum;
        for (int k = 0; k < TOPK; k++) {
            int e = sel[k];
            int pos = atomicAdd(&cnt[e], 1);
            tokid[e * CAP + pos] = t;
            tokw[e * CAP + pos] = sw[k] * invw;
        }
    }
}

__global__ void prefix_kernel(const int* __restrict__ cnt, int* __restrict__ prefix) {
    if (threadIdx.x == 0) {
        int s = 0;
        for (int e = 0; e < E; e++) { prefix[e] = s; s += cnt[e]; }
        prefix[E] = s;
    }
}

// ---------------- stage 1: h = silu(xi@Wg) * (xi@Wu), bf16 MFMA ----------------
template <bool EXPERT>
__global__ __launch_bounds__(256) void stage1_gemm(
    const float* __restrict__ x, const float* __restrict__ wg_all,
    const float* __restrict__ wu_all, bf16* __restrict__ hout,
    const int* __restrict__ cnt, const int* __restrict__ prefix,
    const int* __restrict__ tokid, const float* __restrict__ tokw, int nF) {
    __shared__ __align__(16) bf16 As[128 * LDA];
    __shared__ __align__(16) bf16 Bg[128 * LDA];
    __shared__ __align__(16) bf16 Bu[128 * LDA];

    const int tid = threadIdx.x;
    const int n0 = blockIdx.x * 128;
    const int m0 = blockIdx.y * 128;
    int e = 0, ne = T;
    const float* wg = wg_all;
    const float* wu = wu_all;
    bf16* hb = hout;
    if (EXPERT) {
        e = blockIdx.z;
        ne = cnt[e];
        if (m0 >= ne) return;
        wg = wg_all + (size_t)e * H * F;
        wu = wu_all + (size_t)e * H * F;
        hb = hout + (size_t)prefix[e] * F;
    }

    // per-thread A staging rows (fixed across K loop)
    const float* aptr[4]; float ascl[4]; bool avalid[4];
#pragma unroll
    for (int j = 0; j < 4; j++) {
        int idx = tid + j * 256;
        int r = idx >> 3;
        int kq = (idx & 7) * 4;
        int slot = m0 + r;
        if (EXPERT) {
            if (slot < ne) {
                int t = tokid[e * CAP + slot];
                aptr[j] = x + (size_t)t * H + kq;
                ascl[j] = tokw[e * CAP + slot];
                avalid[j] = true;
            } else { aptr[j] = x; ascl[j] = 0.f; avalid[j] = false; }
        } else {
            aptr[j] = x + (size_t)slot * H + kq;
            ascl[j] = 1.f; avalid[j] = true;
        }
    }

    const int lane = tid & 63;
    const int m = lane & 15;
    const int quad = lane >> 4;
    const int wave = tid >> 6;
    const int wm = (wave & 1) * 64;
    const int wn = (wave >> 1) * 64;

    floatx4 accg[4][4], accu[4][4];
#pragma unroll
    for (int i = 0; i < 4; i++)
#pragma unroll
        for (int j = 0; j < 4; j++) {
            accg[i][j] = (floatx4){0.f, 0.f, 0.f, 0.f};
            accu[i][j] = (floatx4){0.f, 0.f, 0.f, 0.f};
        }

    for (int k0 = 0; k0 < H; k0 += 32) {
        // stage A (gather + scale + convert), [m][k] k-contiguous
#pragma unroll
        for (int j = 0; j < 4; j++) {
            int idx = tid + j * 256;
            int r = idx >> 3;
            int kq = (idx & 7) * 4;
            float4 v = make_float4(0.f, 0.f, 0.f, 0.f);
            if (!EXPERT || avalid[j]) v = *(const float4*)(aptr[j] + k0);
            bf16x4 bv;
            bv[0] = (bf16)(v.x * ascl[j]); bv[1] = (bf16)(v.y * ascl[j]);
            bv[2] = (bf16)(v.z * ascl[j]); bv[3] = (bf16)(v.w * ascl[j]);
            *(bf16x4*)&As[r * LDA + kq] = bv;
        }
        // stage B transposed to [n][k]
#pragma unroll
        for (int j = 0; j < 4; j++) {
            int idx = tid + j * 256;
            int kk = idx >> 5;
            int n4 = (idx & 31) * 4;
            float4 vg = *(const float4*)(wg + (size_t)(k0 + kk) * nF + n0 + n4);
            Bg[(n4 + 0) * LDA + kk] = (bf16)vg.x;
            Bg[(n4 + 1) * LDA + kk] = (bf16)vg.y;
            Bg[(n4 + 2) * LDA + kk] = (bf16)vg.z;
            Bg[(n4 + 3) * LDA + kk] = (bf16)vg.w;
            float4 vu = *(const float4*)(wu + (size_t)(k0 + kk) * nF + n0 + n4);
            Bu[(n4 + 0) * LDA + kk] = (bf16)vu.x;
            Bu[(n4 + 1) * LDA + kk] = (bf16)vu.y;
            Bu[(n4 + 2) * LDA + kk] = (bf16)vu.z;
            Bu[(n4 + 3) * LDA + kk] = (bf16)vu.w;
        }
        __syncthreads();
        bf16x8 af[4], bgf[4], buf_[4];
#pragma unroll
        for (int mi = 0; mi < 4; mi++)
            af[mi] = *(const bf16x8*)&As[(wm + mi * 16 + m) * LDA + quad * 8];
#pragma unroll
        for (int ni = 0; ni < 4; ni++) {
            bgf[ni] = *(const bf16x8*)&Bg[(wn + ni * 16 + m) * LDA + quad * 8];
            buf_[ni] = *(const bf16x8*)&Bu[(wn + ni * 16 + m) * LDA + quad * 8];
        }
#pragma unroll
        for (int mi = 0; mi < 4; mi++)
#pragma unroll
            for (int ni = 0; ni < 4; ni++) {
                accg[mi][ni] = mfma16(af[mi], bgf[ni], accg[mi][ni]);
                accu[mi][ni] = mfma16(af[mi], buf_[ni], accu[mi][ni]);
            }
        __syncthreads();
    }

    // epilogue: silu(g)*u -> bf16
#pragma unroll
    for (int mi = 0; mi < 4; mi++)
#pragma unroll
        for (int ni = 0; ni < 4; ni++)
#pragma unroll
            for (int r = 0; r < 4; r++) {
                int row = m0 + wm + mi * 16 + quad * 4 + r;
                int col = n0 + wn + ni * 16 + m;
                if (!EXPERT || row < ne) {
                    float g = accg[mi][ni][r];
                    float u = accu[mi][ni][r];
                    float hv = g / (1.f + __expf(-g)) * u;
                    hb[(size_t)row * nF + col] = (bf16)hv;
                }
            }
}

// ---------------- stage 2: out (+)= (h @ Wd) [* m] ----------------
template <bool EXPERT>
__global__ __launch_bounds__(256) void stage2_gemm(
    const bf16* __restrict__ hin, const float* __restrict__ wd_all,
    float* __restrict__ out, const int* __restrict__ cnt,
    const int* __restrict__ prefix, const int* __restrict__ tokid,
    const float* __restrict__ tokw, int nK) {
    __shared__ __align__(16) bf16 As[128 * LDA];
    __shared__ __align__(16) bf16 Bs[128 * LDA];
    const int tid = threadIdx.x;
    const int n0 = blockIdx.x * 128;  // over H
    const int m0 = blockIdx.y * 128;  // over rows/slots
    int e = 0, ne = T;
    const float* wd = wd_all;
    const bf16* hb = hin;
    if (EXPERT) {
        e = blockIdx.z;
        ne = cnt[e];
        if (m0 >= ne) return;
        wd = wd_all + (size_t)e * F * H;
        hb = hin + (size_t)prefix[e] * F;
    }
    const int lane = tid & 63;
    const int m = lane & 15;
    const int quad = lane >> 4;
    const int wave = tid >> 6;
    const int wm = (wave & 1) * 64;
    const int wn = (wave >> 1) * 64;

    floatx4 acc[4][4];
#pragma unroll
    for (int i = 0; i < 4; i++)
#pragma unroll
        for (int j = 0; j < 4; j++) acc[i][j] = (floatx4){0.f, 0.f, 0.f, 0.f};

    for (int k0 = 0; k0 < nK; k0 += 32) {
        // stage A (bf16 copy)
#pragma unroll
        for (int j = 0; j < 2; j++) {
            int idx = tid + j * 256;
            int r = idx >> 2;
            int k8 = (idx & 3) * 8;
            bf16x8 v;
#pragma unroll
            for (int q = 0; q < 8; q++) v[q] = (bf16)0.f;
            int row = m0 + r;
            if (!EXPERT || row < ne)
                v = *(const bf16x8*)(hb + (size_t)row * nK + k0 + k8);
            *(bf16x8*)&As[r * LDA + k8] = v;
        }
        // stage B transposed to [n][k]
#pragma unroll
        for (int j = 0; j < 4; j++) {
            int idx = tid + j * 256;
            int kk = idx >> 5;
            int n4 = (idx & 31) * 4;
            float4 v = *(const float4*)(wd + (size_t)(k0 + kk) * H + n0 + n4);
            Bs[(n4 + 0) * LDA + kk] = (bf16)v.x;
            Bs[(n4 + 1) * LDA + kk] = (bf16)v.y;
            Bs[(n4 + 2) * LDA + kk] = (bf16)v.z;
            Bs[(n4 + 3) * LDA + kk] = (bf16)v.w;
        }
        __syncthreads();
        bf16x8 af[4], bf_[4];
#pragma unroll
        for (int mi = 0; mi < 4; mi++)
            af[mi] = *(const bf16x8*)&As[(wm + mi * 16 + m) * LDA + quad * 8];
#pragma unroll
        for (int ni = 0; ni < 4; ni++)
            bf_[ni] = *(const bf16x8*)&Bs[(wn + ni * 16 + m) * LDA + quad * 8];
#pragma unroll
        for (int mi = 0; mi < 4; mi++)
#pragma unroll
            for (int ni = 0; ni < 4; ni++)
                acc[mi][ni] = mfma16(af[mi], bf_[ni], acc[mi][ni]);
        __syncthreads();
    }

#pragma unroll
    for (int mi = 0; mi < 4; mi++)
#pragma unroll
        for (int ni = 0; ni < 4; ni++)
#pragma unroll
            for (int r = 0; r < 4; r++) {
                int row = m0 + wm + mi * 16 + quad * 4 + r;
                int col = n0 + wn + ni * 16 + m;
                if (EXPERT) {
                    if (row < ne) {
                        int t = tokid[e * CAP + row];
                        float wgt = tokw[e * CAP + row];
                        atomicAdd(out + (size_t)t * H + col, acc[mi][ni][r] * wgt);
                    }
                } else {
                    out[(size_t)row * H + col] = acc[mi][ni][r];
                }
            }
}

extern "C" void kernel_launch(void* const* d_in, const int* in_sizes, int n_in,
                              void* d_out, int out_size, void* d_ws, size_t ws_size,
                              hipStream_t stream) {
    const float* x = (const float*)d_in[0];
    const float* w_router = (const float*)d_in[1];
    const float* Wg = (const float*)d_in[2];
    const float* Wu = (const float*)d_in[3];
    const float* Wd = (const float*)d_in[4];
    const float* Wg_s = (const float*)d_in[5];
    const float* Wu_s = (const float*)d_in[6];
    const float* Wd_s = (const float*)d_in[7];
    float* out = (float*)d_out;

    char* w = (char*)d_ws;
    int* cnt = (int*)(w + 0);                       // 16 ints
    int* prefix = (int*)(w + 64);                   // 17 ints
    int* tokid = (int*)(w + 256);                   // E*CAP ints
    float* tokw = (float*)(w + 256 + (size_t)E * CAP * 4);
    bf16* Hs = (bf16*)(w + 262400);                 // T*FS bf16  (16.8 MB)
    bf16* Hb = (bf16*)(w + 262400 + (size_t)T * FS * 2);  // T*TOPK*F bf16 (23 MB)

    hipMemsetAsync(cnt, 0, 64, stream);
    router_kernel<<<T / 4, 256, 0, stream>>>(x, w_router, cnt, tokid, tokw);
    prefix_kernel<<<1, 64, 0, stream>>>(cnt, prefix);

    stage1_gemm<false><<<dim3(FS / 128, T / 128, 1), 256, 0, stream>>>(
        x, Wg_s, Wu_s, Hs, nullptr, nullptr, nullptr, nullptr, FS);
    stage1_gemm<true><<<dim3(F / 128, T / 128, E), 256, 0, stream>>>(
        x, Wg, Wu, Hb, cnt, prefix, tokid, tokw, F);

    // shared stage2 writes every out element exactly once (no memset needed);
    // expert stage2 atomically accumulates on top (stream-ordered after it).
    stage2_gemm<false><<<dim3(H / 128, T / 128, 1), 256, 0, stream>>>(
        Hs, Wd_s, out, nullptr, nullptr, nullptr, nullptr, FS);
    stage2_gemm<true><<<dim3(H / 128, T / 128, E), 256, 0, stream>>>(
        Hb, Wd, out, cnt, prefix, tokid, tokw, F);
}